// Round 6
// baseline (194.866 us; speedup 1.0000x reference)
//
#include <hip/hip_runtime.h>
#include <math.h>

#define KD 64
#define VD 64
#define MM 2048          // rows (fixed by problem)
#define NITER (MM / 64)  // rows per lane-group = 32

typedef float vfloat4 __attribute__((ext_vector_type(4)));

__device__ __forceinline__ vfloat4 ntload4(const float* p) {
    return __builtin_nontemporal_load(reinterpret_cast<const vfloat4*>(p));
}
__device__ __forceinline__ void ntstore4(float* p, vfloat4 v) {
    __builtin_nontemporal_store(v, reinterpret_cast<vfloat4*>(p));
}
__device__ __forceinline__ float fastsig(float x) {
    return __builtin_amdgcn_rcpf(1.0f + __expf(-x));
}

// ---------------------------------------------------------------------------
// One block per batch (1024 threads = 16 waves, 64 lane-groups of 16 lanes).
// Lane-group g owns rows n === g (mod 64); 32 rows each.
// Phase 1: stream value_memory (1R+1W): sim -> p (LDS), branchless copy.
// Phase 2: stream key_memory  (1R+1W): acc += p*key, branchless copy.
// Epilogue: in-block reduction -> final gated read vector. Single dispatch.
// __launch_bounds__(1024,2): force VGPR<=64 so 2 blocks/CU (32 waves/CU)
// stay resident -> max outstanding memory requests for the streaming phases.
// ---------------------------------------------------------------------------
__global__ __launch_bounds__(1024, 2) void fused_all(
    const float* __restrict__ value_memory,
    const float* __restrict__ key_memory,
    const float* __restrict__ new_value,
    const float* __restrict__ new_key,
    const int*   __restrict__ iteration,
    const float* __restrict__ conf_w,
    const float* __restrict__ conf_b,
    const float* __restrict__ gate,
    float* __restrict__ new_value_memory,
    float* __restrict__ new_key_memory,
    float* __restrict__ out_read,
    int max_it)
{
    const int b   = blockIdx.x;
    const int tid = threadIdx.x;
    const int l   = tid & 63;
    const int w   = tid >> 6;            // wave 0..15
    const int c4  = (l & 15) * 4;        // column offset
    const int g   = w * 4 + (l >> 4);    // lane-group 0..63 (row mod 64)

    const int it   = iteration[b];
    const float cw = conf_w[0], cb = conf_b[0];

    __shared__ float pS[MM];             // 8 KB
    __shared__ float sS[16], sPC[16];
    __shared__ float racc[16][64];       // 4 KB

    const vfloat4 nv = *reinterpret_cast<const vfloat4*>(new_value + (size_t)b * VD + c4);
    const vfloat4 nk = *reinterpret_cast<const vfloat4*>(new_key   + (size_t)b * KD + c4);
    const vfloat4 z4 = (vfloat4){0.f, 0.f, 0.f, 0.f};

    const size_t base = (size_t)g * 64 + c4;
    const float* vmb  = value_memory     + (size_t)b * MM * VD;
    const float* kmb  = key_memory       + (size_t)b * MM * KD;
    float*       ovmb = new_value_memory + (size_t)b * MM * VD;
    float*       okmb = new_key_memory   + (size_t)b * MM * KD;

    // ---------------- Phase 1: value stream ----------------
    float sloc = 0.f, pcloc = 0.f;
    #pragma unroll 8
    for (int i = 0; i < NITER; ++i) {
        const int n = i * 64 + g;
        const size_t off = base + (size_t)i * 64 * 64;
        vfloat4 v = ntload4(vmb + off);

        float part = fmaf(v.x, nv.x, fmaf(v.y, nv.y, fmaf(v.z, nv.z, v.w * nv.w)));
        part += __shfl_xor(part, 1);
        part += __shfl_xor(part, 2);
        part += __shfl_xor(part, 4);
        part += __shfl_xor(part, 8);      // all 16 lanes of group hold dot

        const float s = (n <= it) ? part : 0.0f;
        const float p = __expf(s);
        if ((l & 15) == 0) pS[n] = p;
        sloc  += p;
        pcloc += p * fastsig(fmaf(s, cw, cb));

        // branchless: row it -> new_value, row max_it -> 0, else copy
        vfloat4 ov = (n == max_it) ? z4 : v;
        ov = (n == it) ? nv : ov;
        ntstore4(ovmb + off, ov);
    }

    // ---------------- Phase 2: key stream ----------------
    vfloat4 acc = z4;
    #pragma unroll 8
    for (int i = 0; i < NITER; ++i) {
        const int n = i * 64 + g;
        const size_t off = base + (size_t)i * 64 * 64;
        vfloat4 k = ntload4(kmb + off);
        const float p = pS[n];            // same-wave LDS producer; broadcast read
        acc.x = fmaf(p, k.x, acc.x); acc.y = fmaf(p, k.y, acc.y);
        acc.z = fmaf(p, k.z, acc.z); acc.w = fmaf(p, k.w, acc.w);

        vfloat4 ov = (n == max_it) ? z4 : k;
        ov = (n == it) ? nk : ov;
        ntstore4(okmb + off, ov);
    }

    // ---------------- reductions ----------------
    // scalar partials: identical within 16-lane group; xor16/32 sums the
    // wave's 4 groups exactly once.
    sloc  += __shfl_xor(sloc, 16);  sloc  += __shfl_xor(sloc, 32);
    pcloc += __shfl_xor(pcloc, 16); pcloc += __shfl_xor(pcloc, 32);
    // column partials: lanes sharing (l&15) hold the same columns.
    acc.x += __shfl_xor(acc.x, 16); acc.y += __shfl_xor(acc.y, 16);
    acc.z += __shfl_xor(acc.z, 16); acc.w += __shfl_xor(acc.w, 16);
    acc.x += __shfl_xor(acc.x, 32); acc.y += __shfl_xor(acc.y, 32);
    acc.z += __shfl_xor(acc.z, 32); acc.w += __shfl_xor(acc.w, 32);

    if (l == 0) { sS[w] = sloc; sPC[w] = pcloc; }
    if (l < 16) {
        racc[w][c4 + 0] = acc.x; racc[w][c4 + 1] = acc.y;
        racc[w][c4 + 2] = acc.z; racc[w][c4 + 3] = acc.w;
    }
    __syncthreads();

    // ---------------- epilogue: final read vector ----------------
    if (tid < KD + 1) {
        float S = 0.f;
        #pragma unroll
        for (int ww = 0; ww < 16; ++ww) S += sS[ww];
        float r = 0.f;
        if (tid < KD) {
            #pragma unroll
            for (int ww = 0; ww < 16; ++ww) r += racc[ww][tid];
        } else {
            #pragma unroll
            for (int ww = 0; ww < 16; ++ww) r += sPC[ww];
        }
        const float gt = gate[(size_t)b * (KD + 1) + tid];
        float val = fastsig(gt) * (r / S);
        if (it <= 1) val = 0.0f;
        out_read[(size_t)b * (KD + 1) + tid] = val;
    }
}

extern "C" void kernel_launch(void* const* d_in, const int* in_sizes, int n_in,
                              void* d_out, int out_size, void* d_ws, size_t ws_size,
                              hipStream_t stream) {
    const float* new_key      = (const float*)d_in[0];
    const float* new_value    = (const float*)d_in[1];
    const float* key_memory   = (const float*)d_in[2];
    const float* value_memory = (const float*)d_in[3];
    const float* gate         = (const float*)d_in[4];
    const float* conf_w       = (const float*)d_in[5];
    const float* conf_b       = (const float*)d_in[6];
    const int*   iteration    = (const int*)d_in[7];

    const int B = in_sizes[0] / KD;              // 512
    const int M = in_sizes[2] / in_sizes[0];     // 2048 (== MM)
    const int max_it = M - 1;

    float* out_km   = (float*)d_out;
    float* out_vm   = out_km + (size_t)B * M * KD;
    float* out_read = out_vm + (size_t)B * M * VD;

    fused_all<<<B, 1024, 0, stream>>>(
        value_memory, key_memory, new_value, new_key, iteration,
        conf_w, conf_b, gate, out_vm, out_km, out_read, max_it);
}